// Round 16
// baseline (504.201 us; speedup 1.0000x reference)
//
#include <hip/hip_runtime.h>
#include <hip/hip_bf16.h>

#define NN   20000
#define EE   320000
#define EN   340000   // EE + NN (self loops)
#define HH   8
#define CC   56
#define HC   448
#define DEA  5
#define EAS  8        // padded csr_ea stride (floats; 32 B lines)
#define DINN 32
#define GG   32
#define NEG  0.2f

#define SS   896      // xl|xr row stride
#define MT   157      // gemm2 M-tiles (ceil(20000/128))
#define NT   7        // gemm2 N-tiles (896/128)

typedef short bf16x8 __attribute__((ext_vector_type(8)));
typedef float f32x4  __attribute__((ext_vector_type(4)));
typedef float f32x8  __attribute__((ext_vector_type(8)));

static __device__ __forceinline__ unsigned short f2bf(float f) {
  unsigned int u = __float_as_uint(f);
  u += 0x7fffu + ((u >> 16) & 1u);   // round-to-nearest-even
  return (unsigned short)(u >> 16);
}

static __device__ __forceinline__ f32x8 bf8_to_f32x8(uint4 u) {
  f32x8 o;
  o[0] = __uint_as_float(u.x << 16); o[1] = __uint_as_float(u.x & 0xffff0000u);
  o[2] = __uint_as_float(u.y << 16); o[3] = __uint_as_float(u.y & 0xffff0000u);
  o[4] = __uint_as_float(u.z << 16); o[5] = __uint_as_float(u.z & 0xffff0000u);
  o[6] = __uint_as_float(u.w << 16); o[7] = __uint_as_float(u.w & 0xffff0000u);
  return o;
}

__global__ void k_deg(const int* __restrict__ dst, int* deg) {
  int e = blockIdx.x * 256 + threadIdx.x;
  if (e < EE) atomicAdd(&deg[dst[e]], 1);
}

// exclusive scan of (deg[n]+1) -> offs[0..NN] and cursor[0..NN-1]
__global__ __launch_bounds__(1024) void k_scan(const int* __restrict__ deg, int* offs,
                                               int* cursor) {
  __shared__ int tot[1024];
  int t = threadIdx.x;
  int base = t * 20;
  int loc[20];
  int s = 0;
  #pragma unroll
  for (int i = 0; i < 20; i++) {
    int idx = base + i;
    int v = (idx < NN) ? deg[idx] + 1 : 0;
    loc[i] = s;
    s += v;
  }
  tot[t] = s;
  __syncthreads();
  for (int o = 1; o < 1024; o <<= 1) {
    int v = (t >= o) ? tot[t - o] : 0;
    __syncthreads();
    tot[t] += v;
    __syncthreads();
  }
  int basesum = (t == 0) ? 0 : tot[t - 1];
  #pragma unroll
  for (int i = 0; i < 20; i++) {
    int idx = base + i;
    if (idx < NN) { offs[idx] = basesum + loc[i]; cursor[idx] = basesum + loc[i]; }
  }
  if (t == 1023) offs[NN] = tot[1023];
}

// scatter real edges; slots [offs[n], offs[n+1]-1); full-32B line writes
__global__ void k_scatter(const int* __restrict__ src, const int* __restrict__ dst,
                          const float* __restrict__ ea,
                          int* cursor, int* __restrict__ csr_src, float* __restrict__ csr_ea) {
  int i = blockIdx.x * 256 + threadIdx.x;
  if (i >= EE) return;
  int d = dst[i], s = src[i];
  float a[DEA];
  #pragma unroll
  for (int j = 0; j < DEA; j++) a[j] = ea[(size_t)i * DEA + j];
  int pos = atomicAdd(&cursor[d], 1);
  csr_src[pos] = s;
  float* o = csr_ea + (size_t)pos * EAS;
  *(f32x4*)o       = (f32x4){a[0], a[1], a[2], a[3]};
  *(f32x4*)(o + 4) = (f32x4){a[4], 0.f, 0.f, 0.f};
}

// fused: self-loop attrs + x->bf16 cast + W1t/W2t transposed bf16 casts
#define XCN (NN * DINN)
#define W1N (SS * DINN)
#define W2N (SS * HC)
__global__ void k_aux(const int* __restrict__ offs,
                      int* __restrict__ csr_src, float* __restrict__ csr_ea,
                      const float* __restrict__ x, unsigned short* __restrict__ xb,
                      const float* __restrict__ Wl1, const float* __restrict__ Wr1,
                      unsigned short* __restrict__ W1t,
                      const float* __restrict__ Wl2, const float* __restrict__ Wr2,
                      unsigned short* __restrict__ W2t) {
  int i = blockIdx.x * 256 + threadIdx.x;
  if (i < NN) {
    int n = i;
    int e0 = offs[n], e1 = offs[n + 1] - 1;
    float a0 = 0.f, a1 = 0.f, a2 = 0.f, a3 = 0.f, a4 = 0.f;
    for (int e = e0; e < e1; e++) {
      const float* p = csr_ea + (size_t)e * EAS;
      a0 += p[0]; a1 += p[1]; a2 += p[2]; a3 += p[3]; a4 += p[4];
    }
    float inv = 1.f / fmaxf((float)(e1 - e0), 1.f);
    csr_src[e1] = n;
    float* o = csr_ea + (size_t)e1 * EAS;
    *(f32x4*)o       = (f32x4){a0 * inv, a1 * inv, a2 * inv, a3 * inv};
    *(f32x4*)(o + 4) = (f32x4){a4 * inv, 0.f, 0.f, 0.f};
    return;
  }
  i -= NN;
  if (i < XCN) { xb[i] = f2bf(x[i]); return; }
  i -= XCN;
  if (i < W1N) {
    int col = i / DINN, k = i - col * DINN;
    int cc = (col < HC) ? col : col - HC;
    const float* W = (col < HC) ? Wl1 : Wr1;
    W1t[i] = f2bf(W[(size_t)k * HC + cc]);
    return;
  }
  i -= W1N;
  if (i < W2N) {
    int col = i / HC, k = i - col * HC;
    int cc = (col < HC) ? col : col - HC;
    const float* W = (col < HC) ? Wl2 : Wr2;
    W2t[i] = f2bf(W[(size_t)k * HC + cc]);
  }
}

// MFMA gemm1 (transposed operands): A = W1t rows (m = out-col), B = xb rows
// (n = node). D: row=q*4+reg -> out-col (4 consecutive per lane -> one 8B
// store), col=r -> node. B-frag shared across the 4 m-tiles.
__global__ __launch_bounds__(256) void k_gemm1(const unsigned short* __restrict__ xb,
                                               const unsigned short* __restrict__ W1t,
                                               unsigned short* __restrict__ out) {
  int w = threadIdx.x >> 6, lane = threadIdx.x & 63;
  int q = lane >> 4, r = lane & 15;
  int m0 = blockIdx.x * 64;                    // out-col base
  int node = blockIdx.y * 64 + w * 16 + r;
  int nc = node < NN ? node : NN - 1;
  bf16x8 b = *(const bf16x8*)(xb + (size_t)nc * DINN + q * 8);
  #pragma unroll
  for (int j = 0; j < 4; j++) {
    bf16x8 a = *(const bf16x8*)(W1t + (size_t)(m0 + j * 16 + r) * DINN + q * 8);
    f32x4 acc = {0.f, 0.f, 0.f, 0.f};
    acc = __builtin_amdgcn_mfma_f32_16x16x32_bf16(a, b, acc, 0, 0, 0);
    uint2 st;
    st.x = ((unsigned int)f2bf(acc[1]) << 16) | f2bf(acc[0]);
    st.y = ((unsigned int)f2bf(acc[3]) << 16) | f2bf(acc[2]);
    if (node < NN)
      *(uint2*)(out + (size_t)node * SS + m0 + j * 16 + q * 4) = st;
  }
}

// Fused GATv2 attention v10: wave = one node, all 8 heads; lane = (head, 8ch);
// SINGLE-edge loop — minimizes live VGPRs to cross below the 64-reg occupancy
// cliff (VGPR 64 -> ~16 waves/CU; <64 -> ~32). TLP > ILP for this kernel
// (rounds 10/11 evidence).
__global__ __launch_bounds__(256) void k_attn(
    const unsigned short* __restrict__ xlr,
    const int* __restrict__ offs, const int* __restrict__ csr_src,
    const float* __restrict__ csr_ea,
    const float* __restrict__ We, const float* __restrict__ att,
    const float* __restrict__ bias,
    unsigned short* __restrict__ outb, float* __restrict__ outf, int layer1) {
  int n = blockIdx.x * 4 + (threadIdx.x >> 6);
  if (n >= NN) return;
  int lane = threadIdx.x & 63;
  int head = lane >> 3, sub = lane & 7;
  bool v = sub < 7;                        // 7 subs x 8ch = 56 channels/head
  int cb = head * 56 + (v ? sub : 6) * 8;  // clamped channel base (loads safe)

  f32x8 z = {0.f,0.f,0.f,0.f,0.f,0.f,0.f,0.f};
  f32x8 xr = bf8_to_f32x8(*(const uint4*)(xlr + (size_t)n * SS + HC + cb));
  f32x8 at = *(const f32x8*)(att + cb);
  if (!v) at = z;
  f32x8 w0 = *(const f32x8*)(We + 0 * HC + cb);
  f32x8 w1 = *(const f32x8*)(We + 1 * HC + cb);
  f32x8 w2 = *(const f32x8*)(We + 2 * HC + cb);
  f32x8 w3 = *(const f32x8*)(We + 3 * HC + cb);
  f32x8 w4 = *(const f32x8*)(We + 4 * HC + cb);

  int e0 = offs[n], e1 = offs[n + 1];
  float l = 0.f;
  f32x8 acc = z;

  for (int e = e0; e < e1; e++) {
    int s0 = csr_src[e];
    const float* ep = csr_ea + (size_t)e * EAS;
    f32x4 ea0 = *(const f32x4*)ep;
    float e4 = ep[4];
    uint4 g0 = *(const uint4*)(xlr + (size_t)s0 * SS + cb);
    f32x8 xl = bf8_to_f32x8(g0);

    f32x8 t = xl + xr;
    t += ea0.x * w0; t += ea0.y * w1; t += ea0.z * w2; t += ea0.w * w3; t += e4 * w4;
    #pragma unroll
    for (int i = 0; i < 8; i++) t[i] = fmaxf(t[i], NEG * t[i]);
    float p = 0.f;
    #pragma unroll
    for (int i = 0; i < 8; i++) p += t[i] * at[i];
    p += __shfl_xor(p, 1, 64);
    p += __shfl_xor(p, 2, 64);
    p += __shfl_xor(p, 4, 64);
    float wv = __expf(fminf(p, 60.f));
    acc += wv * xl;
    l += wv;
  }

  f32x8 b8 = *(const f32x8*)(bias + cb);
  f32x8 o = acc * (1.f / (l + 1e-16f)) + b8;
  if (layer1) {
    if (v) {
      #pragma unroll
      for (int i = 0; i < 8; i++) o[i] = o[i] > 0.f ? o[i] : (__expf(o[i]) - 1.f);
      uint4 pk;
      pk.x = ((unsigned int)f2bf(o[1]) << 16) | f2bf(o[0]);
      pk.y = ((unsigned int)f2bf(o[3]) << 16) | f2bf(o[2]);
      pk.z = ((unsigned int)f2bf(o[5]) << 16) | f2bf(o[4]);
      pk.w = ((unsigned int)f2bf(o[7]) << 16) | f2bf(o[6]);
      *(uint4*)(outb + (size_t)n * HC + cb) = pk;
    }
  } else if (v) {
    float* dst = outf + (size_t)n * HC + cb;
    *(f32x4*)dst       = (f32x4){o[0], o[1], o[2], o[3]};
    *(f32x4*)(dst + 4) = (f32x4){o[4], o[5], o[6], o[7]};
  }
}

// per-channel sum / sumsq over NN rows of bf16 h1
__global__ __launch_bounds__(448) void k_bnstats(const unsigned short* __restrict__ h,
                                                 float* stat) {
  int c = threadIdx.x;
  int rows_per = (NN + gridDim.x - 1) / gridDim.x;
  int r0 = blockIdx.x * rows_per, r1 = min(NN, r0 + rows_per);
  float s = 0.f, sq = 0.f;
  for (int r = r0; r < r1; r++) {
    unsigned int u = h[(size_t)r * HC + c];
    float v = __uint_as_float(u << 16);
    s += v; sq += v * v;
  }
  atomicAdd(&stat[c], s);
  atomicAdd(&stat[HC + c], sq);
}

// fold BN into W2: W2s[j][k] = bf16(sc[k]*W2t[j][k]); bias2[j] = sum_k sh[k]*W2t[j][k]
__global__ __launch_bounds__(64) void k_w2fix(const unsigned short* __restrict__ W2t,
                                              const float* __restrict__ stat,
                                              const float* __restrict__ gam,
                                              const float* __restrict__ bet,
                                              unsigned short* __restrict__ W2s,
                                              float* __restrict__ bias2) {
  int j = blockIdx.x;
  int t = threadIdx.x;
  float bacc = 0.f;
  #pragma unroll
  for (int it = 0; it < 7; it++) {
    int k = t + it * 64;
    float w = __uint_as_float((unsigned int)W2t[(size_t)j * HC + k] << 16);
    float mean = stat[k] * (1.f / NN);
    float var  = stat[HC + k] * (1.f / NN) - mean * mean;
    float sc = rsqrtf(var + 1e-5f) * gam[k];
    float sh = bet[k] - mean * sc;
    bacc += sh * w;
    W2s[(size_t)j * HC + k] = f2bf(sc * w);
  }
  #pragma unroll
  for (int m = 32; m >= 1; m >>= 1) bacc += __shfl_xor(bacc, m, 64);
  if (t == 0) bias2[j] = bacc;
}

// LDS-staged bf16 MFMA GEMM with XOR-swizzled LDS (kills 16-way bank conflict
// of the 128B-row layout). xlr2 = h1b @ W2s^T + bias2. BK=64, 128x128 tile.
__global__ __launch_bounds__(256) void k_gemm2(const unsigned short* __restrict__ A,
                                               const unsigned short* __restrict__ Bt,
                                               const float* __restrict__ bias2,
                                               unsigned short* __restrict__ out) {
  __shared__ unsigned short As[128 * 64];
  __shared__ unsigned short Bs[128 * 64];
  int bid = blockIdx.x;
  int g = bid / 56, rem = bid - g * 56;
  int xs = min(8, MT - g * 8);
  int bx = g * 8 + rem % xs;
  int by = rem / xs;
  int t = threadIdx.x;
  int w = t >> 6, lane = t & 63;
  int wm = w >> 1, wn = w & 1;
  int q = lane >> 4, r = lane & 15;
  int m0 = bx * 128;
  int n0 = by * 128;

  const unsigned short *ag[4], *bg[4];
  unsigned short *la[4], *lb[4];
  #pragma unroll
  for (int j = 0; j < 4; j++) {
    int s = t + j * 256;
    int row = s >> 3;
    int gcol = (s & 7) ^ (row & 7);       // fetch-permute for bank swizzle
    int ar = m0 + row; if (ar >= NN) ar = NN - 1;
    ag[j] = A + (size_t)ar * HC + gcol * 8;
    bg[j] = Bt + (size_t)(n0 + row) * HC + gcol * 8;
    la[j] = As + s * 8;
    lb[j] = Bs + s * 8;
  }

  f32x4 zero = {0.f, 0.f, 0.f, 0.f};
  f32x4 acc[4][4];
  #pragma unroll
  for (int i = 0; i < 4; i++)
    #pragma unroll
    for (int j = 0; j < 4; j++) acc[i][j] = zero;

  for (int k0 = 0; k0 < HC; k0 += 64) {
    #pragma unroll
    for (int j = 0; j < 4; j++) {
      __builtin_amdgcn_global_load_lds(
          (const __attribute__((address_space(1))) unsigned int*)(ag[j] + k0),
          (__attribute__((address_space(3))) unsigned int*)la[j], 16, 0, 0);
      __builtin_amdgcn_global_load_lds(
          (const __attribute__((address_space(1))) unsigned int*)(bg[j] + k0),
          (__attribute__((address_space(3))) unsigned int*)lb[j], 16, 0, 0);
    }
    __syncthreads();
    #pragma unroll
    for (int kk = 0; kk < 64; kk += 32) {
      int p = (kk >> 3) + q;
      bf16x8 af[4], bf[4];
      #pragma unroll
      for (int i = 0; i < 4; i++) {
        int row = wm * 64 + i * 16 + r;
        af[i] = *(const bf16x8*)(As + row * 64 + ((p ^ (r & 7)) * 8));
      }
      #pragma unroll
      for (int j = 0; j < 4; j++) {
        int row = wn * 64 + j * 16 + r;
        bf[j] = *(const bf16x8*)(Bs + row * 64 + ((p ^ (r & 7)) * 8));
      }
      #pragma unroll
      for (int i = 0; i < 4; i++)
        #pragma unroll
        for (int j = 0; j < 4; j++)
          acc[i][j] = __builtin_amdgcn_mfma_f32_16x16x32_bf16(af[i], bf[j], acc[i][j], 0, 0, 0);
    }
    __syncthreads();
  }

  #pragma unroll
  for (int j = 0; j < 4; j++) {
    int col = n0 + wn * 64 + j * 16 + r;
    float bs = bias2[col];
    #pragma unroll
    for (int i = 0; i < 4; i++) {
      int row_base = m0 + wm * 64 + i * 16 + q * 4;
      #pragma unroll
      for (int reg = 0; reg < 4; reg++) {
        int row = row_base + reg;
        if (row < NN) out[(size_t)row * SS + col] = f2bf(acc[i][j][reg] + bs);
      }
    }
  }
}

// segment-sum pool over sorted batch; also counts rows per graph (thread 0)
__global__ __launch_bounds__(448) void k_pool(const float* __restrict__ h2,
                                              const int* __restrict__ batch,
                                              float* pooled, int* cnt) {
  int c = threadIdx.x;
  int rows_per = (NN + gridDim.x - 1) / gridDim.x;
  int r0 = blockIdx.x * rows_per, r1 = min(NN, r0 + rows_per);
  if (r0 >= r1) return;
  float loc = 0.f;
  int rc = 0;
  int gcur = batch[r0];
  for (int r = r0; r < r1; r++) {
    int g = batch[r];
    if (g != gcur) {
      atomicAdd(&pooled[gcur * HC + c], loc);
      if (c == 0) atomicAdd(&cnt[gcur], rc);
      loc = 0.f; rc = 0; gcur = g;
    }
    loc += h2[(size_t)r * HC + c];
    rc++;
  }
  atomicAdd(&pooled[gcur * HC + c], loc);
  if (c == 0) atomicAdd(&cnt[gcur], rc);
}

// pooled mean -> BN over 32 graphs -> logits -> log_softmax (single block)
__global__ __launch_bounds__(448) void k_final(const float* __restrict__ pooled_sum,
                                               const int* __restrict__ cnt,
                                               const float* __restrict__ gam,
                                               const float* __restrict__ bet,
                                               const float* __restrict__ Wlin,
                                               const float* __restrict__ blin,
                                               float* __restrict__ out) {
  __shared__ float P[GG * HC];
  __shared__ float L[GG * 18];
  __shared__ float red[GG];
  int c = threadIdx.x;
  float s = 0.f, sq = 0.f;
  for (int g = 0; g < GG; g++) {
    float v = pooled_sum[g * HC + c] / fmaxf((float)cnt[g], 1.f);
    P[g * HC + c] = v; s += v; sq += v * v;
  }
  float mean = s * (1.f / GG);
  float var  = sq * (1.f / GG) - mean * mean;
  float sc = rsqrtf(var + 1e-5f) * gam[c];
  float sh = bet[c] - mean * sc;
  for (int g = 0; g < GG; g++) P[g * HC + c] = P[g * HC + c] * sc + sh;
  __syncthreads();
  for (int o = c; o < GG * 18; o += HC) {
    int g = o / 18, j = o - g * 18;
    float acc = blin[j];
    for (int k = 0; k < HC; k++) acc += P[g * HC + k] * Wlin[k * 18 + j];
    L[o] = acc;
  }
  __syncthreads();
  if (c < GG) {
    float mx = -3.4e38f;
    for (int j = 0; j < 18; j++) mx = fmaxf(mx, L[c * 18 + j]);
    float se = 0.f;
    for (int j = 0; j < 18; j++) se += __expf(L[c * 18 + j] - mx);
    red[c] = mx + logf(se);
  }
  __syncthreads();
  for (int o = c; o < GG * 18; o += HC) out[o] = L[o] - red[o / 18];
}

extern "C" void kernel_launch(void* const* d_in, const int* in_sizes, int n_in,
                              void* d_out, int out_size, void* d_ws, size_t ws_size,
                              hipStream_t stream) {
  (void)in_sizes; (void)n_in; (void)out_size; (void)ws_size;
  const float* x     = (const float*)d_in[0];
  const int*   ei    = (const int*)d_in[1];
  const float* ea    = (const float*)d_in[2];
  const int*   batch = (const int*)d_in[3];
  const float* Wl1   = (const float*)d_in[4];
  const float* Wr1   = (const float*)d_in[5];
  const float* We1   = (const float*)d_in[6];
  const float* att1  = (const float*)d_in[7];
  const float* bias1 = (const float*)d_in[8];
  const float* Wl2   = (const float*)d_in[9];
  const float* Wr2   = (const float*)d_in[10];
  const float* We2   = (const float*)d_in[11];
  const float* att2  = (const float*)d_in[12];
  const float* bias2in = (const float*)d_in[13];
  const float* gam   = (const float*)d_in[14];
  const float* bet   = (const float*)d_in[15];
  const float* Wlin  = (const float*)d_in[16];
  const float* blin  = (const float*)d_in[17];
  float* out = (float*)d_out;
  const int* srcp = ei;
  const int* dstp = ei + EE;

  char* ws = (char*)d_ws;
  size_t off = 0;
  auto alloc = [&](size_t bytes) -> char* {
    char* p = ws + off;
    off = (off + bytes + 255) & ~(size_t)255;
    return p;
  };
  // zero-region: deg | bnstat | pooled | cnt (contiguous, one memset)
  int*   deg     = (int*)  alloc(NN * 4);
  float* bnstat  = (float*)alloc(HC * 2 * 4);
  float* pooled  = (float*)alloc(GG * HC * 4 + GG * 4);
  int*   cnt     = (int*)(pooled + GG * HC);
  size_t zlen    = (size_t)((char*)(cnt + GG) - (char*)deg);

  int*   offs    = (int*)  alloc((NN + 1) * 4);
  int*   cursor  = (int*)  alloc(NN * 4);
  int*   csr_src = (int*)  alloc((size_t)EN * 4);
  float* csr_ea  = (float*)alloc((size_t)EN * EAS * 4);
  unsigned short* xlr = (unsigned short*)alloc((size_t)NN * SS * 2); // bf16
  unsigned short* h1b = (unsigned short*)alloc((size_t)NN * HC * 2); // L1 out bf16
  float* h1f     = (float*)alloc((size_t)NN * HC * 4);               // L2 out fp32
  unsigned short* xb  = (unsigned short*)alloc((size_t)NN * DINN * 2);
  unsigned short* W1t = (unsigned short*)alloc((size_t)SS * DINN * 2);
  unsigned short* W2t = (unsigned short*)alloc((size_t)SS * HC * 2);
  unsigned short* W2s = (unsigned short*)alloc((size_t)SS * HC * 2);
  float* bias2   = (float*)alloc(SS * 4);

  // ---- preprocessing: CSR by dst ----
  hipMemsetAsync(deg, 0, zlen, stream);
  k_deg<<<(EE + 255) / 256, 256, 0, stream>>>(dstp, deg);
  k_scan<<<1, 1024, 0, stream>>>(deg, offs, cursor);
  k_scatter<<<(EE + 255) / 256, 256, 0, stream>>>(srcp, dstp, ea, cursor, csr_src, csr_ea);
  k_aux<<<(NN + XCN + W1N + W2N + 255) / 256, 256, 0, stream>>>(
      offs, csr_src, csr_ea, x, xb, Wl1, Wr1, W1t, Wl2, Wr2, W2t);

  // ---- layer 1 ----
  dim3 g1(SS / 64, (NN + 63) / 64);
  k_gemm1<<<g1, 256, 0, stream>>>(xb, W1t, xlr);
  k_attn<<<(NN + 3) / 4, 256, 0, stream>>>(xlr, offs, csr_src, csr_ea,
                                           We1, att1, bias1, h1b, h1f, 1);
  // ---- BN (stats + fold into W2) ----
  k_bnstats<<<512, HC, 0, stream>>>(h1b, bnstat);
  k_w2fix<<<SS, 64, 0, stream>>>(W2t, bnstat, gam, bet, W2s, bias2);

  // ---- layer 2 ----
  k_gemm2<<<MT * NT, 256, 0, stream>>>(h1b, W2s, bias2, xlr);
  k_attn<<<(NN + 3) / 4, 256, 0, stream>>>(xlr, offs, csr_src, csr_ea,
                                           We2, att2, bias2in, h1b, h1f, 0);

  // ---- pool + final ----
  k_pool<<<640, HC, 0, stream>>>(h1f, batch, pooled, cnt);
  k_final<<<1, HC, 0, stream>>>(pooled, cnt, gam, bet, Wlin, blin, out);
}

// Round 17
// 444.087 us; speedup vs baseline: 1.1354x; 1.1354x over previous
//
#include <hip/hip_runtime.h>
#include <hip/hip_bf16.h>

#define NN   20000
#define EE   320000
#define EN   340000   // EE + NN (self loops)
#define HH   8
#define CC   56
#define HC   448
#define DEA  5
#define EAS  8        // padded csr_ea stride (floats; 32 B lines)
#define DINN 32
#define GG   32
#define NEG  0.2f

#define SS   896      // xl|xr row stride
#define MT   157      // gemm2 M-tiles (ceil(20000/128))
#define NT   7        // gemm2 N-tiles (896/128)

typedef short bf16x8 __attribute__((ext_vector_type(8)));
typedef float f32x4  __attribute__((ext_vector_type(4)));
typedef float f32x8  __attribute__((ext_vector_type(8)));

static __device__ __forceinline__ unsigned short f2bf(float f) {
  unsigned int u = __float_as_uint(f);
  u += 0x7fffu + ((u >> 16) & 1u);   // round-to-nearest-even
  return (unsigned short)(u >> 16);
}

static __device__ __forceinline__ f32x8 bf8_to_f32x8(uint4 u) {
  f32x8 o;
  o[0] = __uint_as_float(u.x << 16); o[1] = __uint_as_float(u.x & 0xffff0000u);
  o[2] = __uint_as_float(u.y << 16); o[3] = __uint_as_float(u.y & 0xffff0000u);
  o[4] = __uint_as_float(u.z << 16); o[5] = __uint_as_float(u.z & 0xffff0000u);
  o[6] = __uint_as_float(u.w << 16); o[7] = __uint_as_float(u.w & 0xffff0000u);
  return o;
}

__global__ void k_deg(const int* __restrict__ dst, int* deg) {
  int e = blockIdx.x * 256 + threadIdx.x;
  if (e < EE) atomicAdd(&deg[dst[e]], 1);
}

// exclusive scan of (deg[n]+1) -> offs[0..NN] and cursor[0..NN-1]
__global__ __launch_bounds__(1024) void k_scan(const int* __restrict__ deg, int* offs,
                                               int* cursor) {
  __shared__ int tot[1024];
  int t = threadIdx.x;
  int base = t * 20;
  int loc[20];
  int s = 0;
  #pragma unroll
  for (int i = 0; i < 20; i++) {
    int idx = base + i;
    int v = (idx < NN) ? deg[idx] + 1 : 0;
    loc[i] = s;
    s += v;
  }
  tot[t] = s;
  __syncthreads();
  for (int o = 1; o < 1024; o <<= 1) {
    int v = (t >= o) ? tot[t - o] : 0;
    __syncthreads();
    tot[t] += v;
    __syncthreads();
  }
  int basesum = (t == 0) ? 0 : tot[t - 1];
  #pragma unroll
  for (int i = 0; i < 20; i++) {
    int idx = base + i;
    if (idx < NN) { offs[idx] = basesum + loc[i]; cursor[idx] = basesum + loc[i]; }
  }
  if (t == 1023) offs[NN] = tot[1023];
}

// scatter real edges; slots [offs[n], offs[n+1]-1); full-32B line writes
__global__ void k_scatter(const int* __restrict__ src, const int* __restrict__ dst,
                          const float* __restrict__ ea,
                          int* cursor, int* __restrict__ csr_src, float* __restrict__ csr_ea) {
  int i = blockIdx.x * 256 + threadIdx.x;
  if (i >= EE) return;
  int d = dst[i], s = src[i];
  float a[DEA];
  #pragma unroll
  for (int j = 0; j < DEA; j++) a[j] = ea[(size_t)i * DEA + j];
  int pos = atomicAdd(&cursor[d], 1);
  csr_src[pos] = s;
  float* o = csr_ea + (size_t)pos * EAS;
  *(f32x4*)o       = (f32x4){a[0], a[1], a[2], a[3]};
  *(f32x4*)(o + 4) = (f32x4){a[4], 0.f, 0.f, 0.f};
}

// fused: self-loop attrs + x->bf16 cast + W1t/W2t transposed bf16 casts
#define XCN (NN * DINN)
#define W1N (SS * DINN)
#define W2N (SS * HC)
__global__ void k_aux(const int* __restrict__ offs,
                      int* __restrict__ csr_src, float* __restrict__ csr_ea,
                      const float* __restrict__ x, unsigned short* __restrict__ xb,
                      const float* __restrict__ Wl1, const float* __restrict__ Wr1,
                      unsigned short* __restrict__ W1t,
                      const float* __restrict__ Wl2, const float* __restrict__ Wr2,
                      unsigned short* __restrict__ W2t) {
  int i = blockIdx.x * 256 + threadIdx.x;
  if (i < NN) {
    int n = i;
    int e0 = offs[n], e1 = offs[n + 1] - 1;
    float a0 = 0.f, a1 = 0.f, a2 = 0.f, a3 = 0.f, a4 = 0.f;
    for (int e = e0; e < e1; e++) {
      const float* p = csr_ea + (size_t)e * EAS;
      a0 += p[0]; a1 += p[1]; a2 += p[2]; a3 += p[3]; a4 += p[4];
    }
    float inv = 1.f / fmaxf((float)(e1 - e0), 1.f);
    csr_src[e1] = n;
    float* o = csr_ea + (size_t)e1 * EAS;
    *(f32x4*)o       = (f32x4){a0 * inv, a1 * inv, a2 * inv, a3 * inv};
    *(f32x4*)(o + 4) = (f32x4){a4 * inv, 0.f, 0.f, 0.f};
    return;
  }
  i -= NN;
  if (i < XCN) { xb[i] = f2bf(x[i]); return; }
  i -= XCN;
  if (i < W1N) {
    int col = i / DINN, k = i - col * DINN;
    int cc = (col < HC) ? col : col - HC;
    const float* W = (col < HC) ? Wl1 : Wr1;
    W1t[i] = f2bf(W[(size_t)k * HC + cc]);
    return;
  }
  i -= W1N;
  if (i < W2N) {
    int col = i / HC, k = i - col * HC;
    int cc = (col < HC) ? col : col - HC;
    const float* W = (col < HC) ? Wl2 : Wr2;
    W2t[i] = f2bf(W[(size_t)k * HC + cc]);
  }
}

// MFMA gemm1 (transposed operands): A = W1t rows (m = out-col), B = xb rows
// (n = node). D: row=q*4+reg -> out-col (4 consecutive per lane -> one 8B
// store), col=r -> node. B-frag shared across the 4 m-tiles.
__global__ __launch_bounds__(256) void k_gemm1(const unsigned short* __restrict__ xb,
                                               const unsigned short* __restrict__ W1t,
                                               unsigned short* __restrict__ out) {
  int w = threadIdx.x >> 6, lane = threadIdx.x & 63;
  int q = lane >> 4, r = lane & 15;
  int m0 = blockIdx.x * 64;                    // out-col base
  int node = blockIdx.y * 64 + w * 16 + r;
  int nc = node < NN ? node : NN - 1;
  bf16x8 b = *(const bf16x8*)(xb + (size_t)nc * DINN + q * 8);
  #pragma unroll
  for (int j = 0; j < 4; j++) {
    bf16x8 a = *(const bf16x8*)(W1t + (size_t)(m0 + j * 16 + r) * DINN + q * 8);
    f32x4 acc = {0.f, 0.f, 0.f, 0.f};
    acc = __builtin_amdgcn_mfma_f32_16x16x32_bf16(a, b, acc, 0, 0, 0);
    uint2 st;
    st.x = ((unsigned int)f2bf(acc[1]) << 16) | f2bf(acc[0]);
    st.y = ((unsigned int)f2bf(acc[3]) << 16) | f2bf(acc[2]);
    if (node < NN)
      *(uint2*)(out + (size_t)node * SS + m0 + j * 16 + q * 4) = st;
  }
}

// Fused GATv2 attention (round-13 proven 2-edge structure) + scalar-pipe edge
// metadata: e is wave-uniform, so csr_src/csr_ea loads are certified uniform
// via readfirstlane -> s_load on the scalar pipe (1 vector load/edge remains).
__global__ __launch_bounds__(256) void k_attn(
    const unsigned short* __restrict__ xlr,
    const int* __restrict__ offs, const int* __restrict__ csr_src,
    const float* __restrict__ csr_ea,
    const float* __restrict__ We, const float* __restrict__ att,
    const float* __restrict__ bias,
    unsigned short* __restrict__ outb, float* __restrict__ outf, int layer1) {
  int n = blockIdx.x * 4 + (threadIdx.x >> 6);
  if (n >= NN) return;
  int lane = threadIdx.x & 63;
  int head = lane >> 3, sub = lane & 7;
  bool v = sub < 7;                        // 7 subs x 8ch = 56 channels/head
  int cb = head * 56 + (v ? sub : 6) * 8;  // clamped channel base (loads safe)

  f32x8 z = {0.f,0.f,0.f,0.f,0.f,0.f,0.f,0.f};
  f32x8 xr = bf8_to_f32x8(*(const uint4*)(xlr + (size_t)n * SS + HC + cb));
  f32x8 at = *(const f32x8*)(att + cb);
  if (!v) at = z;
  f32x8 w0 = *(const f32x8*)(We + 0 * HC + cb);
  f32x8 w1 = *(const f32x8*)(We + 1 * HC + cb);
  f32x8 w2 = *(const f32x8*)(We + 2 * HC + cb);
  f32x8 w3 = *(const f32x8*)(We + 3 * HC + cb);
  f32x8 w4 = *(const f32x8*)(We + 4 * HC + cb);

  int e0 = offs[n], e1 = offs[n + 1];
  float l = 0.f;
  f32x8 acc = z;

  for (int e = e0; e < e1; e += 2) {
    int eb = e + 1;
    bool h2v = eb < e1;
    int eu0 = __builtin_amdgcn_readfirstlane(e);
    int eu1 = __builtin_amdgcn_readfirstlane(h2v ? eb : e);
    int s0 = csr_src[eu0];
    int s1 = csr_src[eu1];
    const float* ep0 = csr_ea + (size_t)eu0 * EAS;
    const float* ep1 = csr_ea + (size_t)eu1 * EAS;
    f32x4 ea0 = *(const f32x4*)ep0;  float e40 = ep0[4];
    f32x4 ea1 = *(const f32x4*)ep1;  float e41 = ep1[4];
    uint4 g0 = *(const uint4*)(xlr + (size_t)s0 * SS + cb);
    uint4 g1 = *(const uint4*)(xlr + (size_t)s1 * SS + cb);
    f32x8 xl0 = bf8_to_f32x8(g0);
    f32x8 xl1 = bf8_to_f32x8(g1);

    f32x8 t0 = xl0 + xr;
    t0 += ea0.x * w0; t0 += ea0.y * w1; t0 += ea0.z * w2; t0 += ea0.w * w3; t0 += e40 * w4;
    f32x8 t1 = xl1 + xr;
    t1 += ea1.x * w0; t1 += ea1.y * w1; t1 += ea1.z * w2; t1 += ea1.w * w3; t1 += e41 * w4;
    #pragma unroll
    for (int i = 0; i < 8; i++) {
      t0[i] = fmaxf(t0[i], NEG * t0[i]);
      t1[i] = fmaxf(t1[i], NEG * t1[i]);
    }
    float p0 = 0.f, p1 = 0.f;
    #pragma unroll
    for (int i = 0; i < 8; i++) { p0 += t0[i] * at[i]; p1 += t1[i] * at[i]; }
    p0 += __shfl_xor(p0, 1, 64);  p1 += __shfl_xor(p1, 1, 64);
    p0 += __shfl_xor(p0, 2, 64);  p1 += __shfl_xor(p1, 2, 64);
    p0 += __shfl_xor(p0, 4, 64);  p1 += __shfl_xor(p1, 4, 64);
    float wv0 = __expf(fminf(p0, 60.f));
    float wv1 = h2v ? __expf(fminf(p1, 60.f)) : 0.f;
    acc += wv0 * xl0;
    acc += wv1 * xl1;
    l += wv0 + wv1;
  }

  f32x8 b8 = *(const f32x8*)(bias + cb);
  f32x8 o = acc * (1.f / (l + 1e-16f)) + b8;
  if (layer1) {
    if (v) {
      #pragma unroll
      for (int i = 0; i < 8; i++) o[i] = o[i] > 0.f ? o[i] : (__expf(o[i]) - 1.f);
      uint4 pk;
      pk.x = ((unsigned int)f2bf(o[1]) << 16) | f2bf(o[0]);
      pk.y = ((unsigned int)f2bf(o[3]) << 16) | f2bf(o[2]);
      pk.z = ((unsigned int)f2bf(o[5]) << 16) | f2bf(o[4]);
      pk.w = ((unsigned int)f2bf(o[7]) << 16) | f2bf(o[6]);
      *(uint4*)(outb + (size_t)n * HC + cb) = pk;
    }
  } else if (v) {
    float* dst = outf + (size_t)n * HC + cb;
    *(f32x4*)dst       = (f32x4){o[0], o[1], o[2], o[3]};
    *(f32x4*)(dst + 4) = (f32x4){o[4], o[5], o[6], o[7]};
  }
}

// per-channel sum / sumsq over NN rows of bf16 h1
__global__ __launch_bounds__(448) void k_bnstats(const unsigned short* __restrict__ h,
                                                 float* stat) {
  int c = threadIdx.x;
  int rows_per = (NN + gridDim.x - 1) / gridDim.x;
  int r0 = blockIdx.x * rows_per, r1 = min(NN, r0 + rows_per);
  float s = 0.f, sq = 0.f;
  for (int r = r0; r < r1; r++) {
    unsigned int u = h[(size_t)r * HC + c];
    float v = __uint_as_float(u << 16);
    s += v; sq += v * v;
  }
  atomicAdd(&stat[c], s);
  atomicAdd(&stat[HC + c], sq);
}

// fold BN into W2: W2s[j][k] = bf16(sc[k]*W2t[j][k]); bias2[j] = sum_k sh[k]*W2t[j][k]
__global__ __launch_bounds__(64) void k_w2fix(const unsigned short* __restrict__ W2t,
                                              const float* __restrict__ stat,
                                              const float* __restrict__ gam,
                                              const float* __restrict__ bet,
                                              unsigned short* __restrict__ W2s,
                                              float* __restrict__ bias2) {
  int j = blockIdx.x;
  int t = threadIdx.x;
  float bacc = 0.f;
  #pragma unroll
  for (int it = 0; it < 7; it++) {
    int k = t + it * 64;
    float w = __uint_as_float((unsigned int)W2t[(size_t)j * HC + k] << 16);
    float mean = stat[k] * (1.f / NN);
    float var  = stat[HC + k] * (1.f / NN) - mean * mean;
    float sc = rsqrtf(var + 1e-5f) * gam[k];
    float sh = bet[k] - mean * sc;
    bacc += sh * w;
    W2s[(size_t)j * HC + k] = f2bf(sc * w);
  }
  #pragma unroll
  for (int m = 32; m >= 1; m >>= 1) bacc += __shfl_xor(bacc, m, 64);
  if (t == 0) bias2[j] = bacc;
}

// LDS-staged bf16 MFMA GEMM with XOR-swizzled LDS (kills 16-way bank conflict
// of the 128B-row layout). xlr2 = h1b @ W2s^T + bias2. BK=64, 128x128 tile.
__global__ __launch_bounds__(256) void k_gemm2(const unsigned short* __restrict__ A,
                                               const unsigned short* __restrict__ Bt,
                                               const float* __restrict__ bias2,
                                               unsigned short* __restrict__ out) {
  __shared__ unsigned short As[128 * 64];
  __shared__ unsigned short Bs[128 * 64];
  int bid = blockIdx.x;
  int g = bid / 56, rem = bid - g * 56;
  int xs = min(8, MT - g * 8);
  int bx = g * 8 + rem % xs;
  int by = rem / xs;
  int t = threadIdx.x;
  int w = t >> 6, lane = t & 63;
  int wm = w >> 1, wn = w & 1;
  int q = lane >> 4, r = lane & 15;
  int m0 = bx * 128;
  int n0 = by * 128;

  const unsigned short *ag[4], *bg[4];
  unsigned short *la[4], *lb[4];
  #pragma unroll
  for (int j = 0; j < 4; j++) {
    int s = t + j * 256;
    int row = s >> 3;
    int gcol = (s & 7) ^ (row & 7);       // fetch-permute for bank swizzle
    int ar = m0 + row; if (ar >= NN) ar = NN - 1;
    ag[j] = A + (size_t)ar * HC + gcol * 8;
    bg[j] = Bt + (size_t)(n0 + row) * HC + gcol * 8;
    la[j] = As + s * 8;
    lb[j] = Bs + s * 8;
  }

  f32x4 zero = {0.f, 0.f, 0.f, 0.f};
  f32x4 acc[4][4];
  #pragma unroll
  for (int i = 0; i < 4; i++)
    #pragma unroll
    for (int j = 0; j < 4; j++) acc[i][j] = zero;

  for (int k0 = 0; k0 < HC; k0 += 64) {
    #pragma unroll
    for (int j = 0; j < 4; j++) {
      __builtin_amdgcn_global_load_lds(
          (const __attribute__((address_space(1))) unsigned int*)(ag[j] + k0),
          (__attribute__((address_space(3))) unsigned int*)la[j], 16, 0, 0);
      __builtin_amdgcn_global_load_lds(
          (const __attribute__((address_space(1))) unsigned int*)(bg[j] + k0),
          (__attribute__((address_space(3))) unsigned int*)lb[j], 16, 0, 0);
    }
    __syncthreads();
    #pragma unroll
    for (int kk = 0; kk < 64; kk += 32) {
      int p = (kk >> 3) + q;
      bf16x8 af[4], bf[4];
      #pragma unroll
      for (int i = 0; i < 4; i++) {
        int row = wm * 64 + i * 16 + r;
        af[i] = *(const bf16x8*)(As + row * 64 + ((p ^ (r & 7)) * 8));
      }
      #pragma unroll
      for (int j = 0; j < 4; j++) {
        int row = wn * 64 + j * 16 + r;
        bf[j] = *(const bf16x8*)(Bs + row * 64 + ((p ^ (r & 7)) * 8));
      }
      #pragma unroll
      for (int i = 0; i < 4; i++)
        #pragma unroll
        for (int j = 0; j < 4; j++)
          acc[i][j] = __builtin_amdgcn_mfma_f32_16x16x32_bf16(af[i], bf[j], acc[i][j], 0, 0, 0);
    }
    __syncthreads();
  }

  #pragma unroll
  for (int j = 0; j < 4; j++) {
    int col = n0 + wn * 64 + j * 16 + r;
    float bs = bias2[col];
    #pragma unroll
    for (int i = 0; i < 4; i++) {
      int row_base = m0 + wm * 64 + i * 16 + q * 4;
      #pragma unroll
      for (int reg = 0; reg < 4; reg++) {
        int row = row_base + reg;
        if (row < NN) out[(size_t)row * SS + col] = f2bf(acc[i][j][reg] + bs);
      }
    }
  }
}

// segment-sum pool over sorted batch; also counts rows per graph (thread 0)
__global__ __launch_bounds__(448) void k_pool(const float* __restrict__ h2,
                                              const int* __restrict__ batch,
                                              float* pooled, int* cnt) {
  int c = threadIdx.x;
  int rows_per = (NN + gridDim.x - 1) / gridDim.x;
  int r0 = blockIdx.x * rows_per, r1 = min(NN, r0 + rows_per);
  if (r0 >= r1) return;
  float loc = 0.f;
  int rc = 0;
  int gcur = batch[r0];
  for (int r = r0; r < r1; r++) {
    int g = batch[r];
    if (g != gcur) {
      atomicAdd(&pooled[gcur * HC + c], loc);
      if (c == 0) atomicAdd(&cnt[gcur], rc);
      loc = 0.f; rc = 0; gcur = g;
    }
    loc += h2[(size_t)r * HC + c];
    rc++;
  }
  atomicAdd(&pooled[gcur * HC + c], loc);
  if (c == 0) atomicAdd(&cnt[gcur], rc);
}

// pooled mean -> BN over 32 graphs -> logits -> log_softmax (single block)
__global__ __launch_bounds__(448) void k_final(const float* __restrict__ pooled_sum,
                                               const int* __restrict__ cnt,
                                               const float* __restrict__ gam,
                                               const float* __restrict__ bet,
                                               const float* __restrict__ Wlin,
                                               const float* __restrict__ blin,
                                               float* __restrict__ out) {
  __shared__ float P[GG * HC];
  __shared__ float L[GG * 18];
  __shared__ float red[GG];
  int c = threadIdx.x;
  float s = 0.f, sq = 0.f;
  for (int g = 0; g < GG; g++) {
    float v = pooled_sum[g * HC + c] / fmaxf((float)cnt[g], 1.f);
    P[g * HC + c] = v; s += v; sq += v * v;
  }
  float mean = s * (1.f / GG);
  float var  = sq * (1.f / GG) - mean * mean;
  float sc = rsqrtf(var + 1e-5f) * gam[c];
  float sh = bet[c] - mean * sc;
  for (int g = 0; g < GG; g++) P[g * HC + c] = P[g * HC + c] * sc + sh;
  __syncthreads();
  for (int o = c; o < GG * 18; o += HC) {
    int g = o / 18, j = o - g * 18;
    float acc = blin[j];
    for (int k = 0; k < HC; k++) acc += P[g * HC + k] * Wlin[k * 18 + j];
    L[o] = acc;
  }
  __syncthreads();
  if (c < GG) {
    float mx = -3.4e38f;
    for (int j = 0; j < 18; j++) mx = fmaxf(mx, L[c * 18 + j]);
    float se = 0.f;
    for (int j = 0; j < 18; j++) se += __expf(L[c * 18 + j] - mx);
    red[c] = mx + logf(se);
  }
  __syncthreads();
  for (int o = c; o < GG * 18; o += HC) out[o] = L[o] - red[o / 18];
}

extern "C" void kernel_launch(void* const* d_in, const int* in_sizes, int n_in,
                              void* d_out, int out_size, void* d_ws, size_t ws_size,
                              hipStream_t stream) {
  (void)in_sizes; (void)n_in; (void)out_size; (void)ws_size;
  const float* x     = (const float*)d_in[0];
  const int*   ei    = (const int*)d_in[1];
  const float* ea    = (const float*)d_in[2];
  const int*   batch = (const int*)d_in[3];
  const float* Wl1   = (const float*)d_in[4];
  const float* Wr1   = (const float*)d_in[5];
  const float* We1   = (const float*)d_in[6];
  const float* att1  = (const float*)d_in[7];
  const float* bias1 = (const float*)d_in[8];
  const float* Wl2   = (const float*)d_in[9];
  const float* Wr2   = (const float*)d_in[10];
  const float* We2   = (const float*)d_in[11];
  const float* att2  = (const float*)d_in[12];
  const float* bias2in = (const float*)d_in[13];
  const float* gam   = (const float*)d_in[14];
  const float* bet   = (const float*)d_in[15];
  const float* Wlin  = (const float*)d_in[16];
  const float* blin  = (const float*)d_in[17];
  float* out = (float*)d_out;
  const int* srcp = ei;
  const int* dstp = ei + EE;

  char* ws = (char*)d_ws;
  size_t off = 0;
  auto alloc = [&](size_t bytes) -> char* {
    char* p = ws + off;
    off = (off + bytes + 255) & ~(size_t)255;
    return p;
  };
  // zero-region: deg | bnstat | pooled | cnt (contiguous, one memset)
  int*   deg     = (int*)  alloc(NN * 4);
  float* bnstat  = (float*)alloc(HC * 2 * 4);
  float* pooled  = (float*)alloc(GG * HC * 4 + GG * 4);
  int*   cnt     = (int*)(pooled + GG * HC);
  size_t zlen    = (size_t)((char*)(cnt + GG) - (char*)deg);

  int*   offs    = (int*)  alloc((NN + 1) * 4);
  int*   cursor  = (int*)  alloc(NN * 4);
  int*   csr_src = (int*)  alloc((size_t)EN * 4);
  float* csr_ea  = (float*)alloc((size_t)EN * EAS * 4);
  unsigned short* xlr = (unsigned short*)alloc((size_t)NN * SS * 2); // bf16
  unsigned short* h1b = (unsigned short*)alloc((size_t)NN * HC * 2); // L1 out bf16
  float* h1f     = (float*)alloc((size_t)NN * HC * 4);               // L2 out fp32
  unsigned short* xb  = (unsigned short*)alloc((size_t)NN * DINN * 2);
  unsigned short* W1t = (unsigned short*)alloc((size_t)SS * DINN * 2);
  unsigned short* W2t = (unsigned short*)alloc((size_t)SS * HC * 2);
  unsigned short* W2s = (unsigned short*)alloc((size_t)SS * HC * 2);
  float* bias2   = (float*)alloc(SS * 4);

  // ---- preprocessing: CSR by dst ----
  hipMemsetAsync(deg, 0, zlen, stream);
  k_deg<<<(EE + 255) / 256, 256, 0, stream>>>(dstp, deg);
  k_scan<<<1, 1024, 0, stream>>>(deg, offs, cursor);
  k_scatter<<<(EE + 255) / 256, 256, 0, stream>>>(srcp, dstp, ea, cursor, csr_src, csr_ea);
  k_aux<<<(NN + XCN + W1N + W2N + 255) / 256, 256, 0, stream>>>(
      offs, csr_src, csr_ea, x, xb, Wl1, Wr1, W1t, Wl2, Wr2, W2t);

  // ---- layer 1 ----
  dim3 g1(SS / 64, (NN + 63) / 64);
  k_gemm1<<<g1, 256, 0, stream>>>(xb, W1t, xlr);
  k_attn<<<(NN + 3) / 4, 256, 0, stream>>>(xlr, offs, csr_src, csr_ea,
                                           We1, att1, bias1, h1b, h1f, 1);
  // ---- BN (stats + fold into W2) ----
  k_bnstats<<<512, HC, 0, stream>>>(h1b, bnstat);
  k_w2fix<<<SS, 64, 0, stream>>>(W2t, bnstat, gam, bet, W2s, bias2);

  // ---- layer 2 ----
  k_gemm2<<<MT * NT, 256, 0, stream>>>(h1b, W2s, bias2, xlr);
  k_attn<<<(NN + 3) / 4, 256, 0, stream>>>(xlr, offs, csr_src, csr_ea,
                                           We2, att2, bias2in, h1b, h1f, 0);

  // ---- pool + final ----
  k_pool<<<640, HC, 0, stream>>>(h1f, batch, pooled, cnt);
  k_final<<<1, HC, 0, stream>>>(pooled, cnt, gam, bet, Wlin, blin, out);
}